// Round 6
// baseline (432.180 us; speedup 1.0000x reference)
//
#include <hip/hip_runtime.h>

// SelfAttention: B=4, S=2048, D=1024, fp32 in/out.
// q=x@Wq^T+bq, k=..., v=...; out = softmax(q k^T) @ v   (no 1/sqrt(d) scale)
//
// Precision plan (all GEMM cores in MFMA):
//  - q/k projections: 2-digit i8 x 2-digit i8, ALL 4 digit products kept
//    (exact integer accumulation; dropped-term error would dominate).
//    x = d0*2^-4 + d1*2^-12, W = e0*2^-9 + e1*2^-17.  delta-q ~ 1.2e-4 std.
//  - q/k requantized to 2 i8 digits (2^-4 / 2^-12) in the epilogue.
//  - scores: 2-digit i8 (M=d0d0 2^-8, X=cross 2^-16, Y=d1d1 2^-24). Exact.
//  - v projection: single bf16 MFMA (dv ~1.4e-3, harmless); PV GEMM in f16.
// P has its own dense buffer (R4 post-mortem: in-place P alias breaks replay).

#define Bb 4
#define Ss 2048
#define Dd 1024
#define Mtot 8192  // B*S

typedef __bf16 bf16x8 __attribute__((ext_vector_type(8)));
typedef _Float16 f16x8 __attribute__((ext_vector_type(8)));
typedef float f32x4 __attribute__((ext_vector_type(4)));
typedef int i32x4 __attribute__((ext_vector_type(4)));
typedef unsigned short u16;
typedef unsigned int u32;
typedef unsigned char u8;
typedef u16 u16x8 __attribute__((ext_vector_type(8)));
typedef u16 u16x4 __attribute__((ext_vector_type(4)));
typedef void __attribute__((address_space(1))) gvoid_t;
typedef void __attribute__((address_space(3))) svoid_t;

// ---- digit scales (all powers of two; products align exactly) ----
// x / q / k digits: coarse 2^-4, fine 2^-12
#define XC 0.0625f
#define XCI 16.f
#define XFI 4096.f
// W digits: coarse 2^-9, fine 2^-17
#define WC 1.953125e-3f
#define WCI 512.f
#define WFI 131072.f
// projection accumulator scales
#define SM_P 1.220703125e-4f          // 2^-13
#define SX_P 4.76837158203125e-7f     // 2^-21
#define SY_P 1.862645149230957e-9f    // 2^-29
// score accumulator scales
#define S00 3.90625e-3f               // 2^-8
#define S01 1.52587890625e-5f         // 2^-16
#define S11 5.9604644775390625e-8f    // 2^-24

__device__ __forceinline__ void gl_lds16(const void* g, void* l) {
  __builtin_amdgcn_global_load_lds((gvoid_t*)g, (svoid_t*)l, 16, 0, 0);
}

__device__ __forceinline__ u16 f2bf(float f) {  // RNE float->bf16
  u32 u = __builtin_bit_cast(u32, f);
  u = (u + 0x7FFFu + ((u >> 16) & 1u)) >> 16;
  return (u16)u;
}
__device__ __forceinline__ u16 f2h(float f) {
  return __builtin_bit_cast(u16, (_Float16)f);
}
__device__ __forceinline__ bf16x8 frag_ld(const char* p) {
  u16x8 v = *(const u16x8*)p;
  return __builtin_bit_cast(bf16x8, v);
}
__device__ __forceinline__ f16x8 frag_ld_h(const char* p) {
  u16x8 v = *(const u16x8*)p;
  return __builtin_bit_cast(f16x8, v);
}
__device__ __forceinline__ f32x4 mfma_bf16(bf16x8 a, bf16x8 b, f32x4 c) {
  return __builtin_amdgcn_mfma_f32_16x16x32_bf16(a, b, c, 0, 0, 0);
}
__device__ __forceinline__ i32x4 mfma_i8(i32x4 a, i32x4 b, i32x4 c) {
  return __builtin_amdgcn_mfma_i32_16x16x64_i8(a, b, c, 0, 0, 0);
}
// split v into two clamped i8 digits: v ~= d0*cs + d1*(1/fi)
__device__ __forceinline__ void dig2(float v, float cs, float ci, float fi,
                                     int& d0, int& d1) {
  float t = fminf(fmaxf(v * ci, -127.f), 127.f);
  d0 = __float2int_rn(t);
  float res = v - (float)d0 * cs;
  float u = fminf(fmaxf(res * fi, -127.f), 127.f);
  d1 = __float2int_rn(u);
}

// stage a tile with 64-byte rows to LDS; ROUNDS*4 KB, linear row-major.
template <int ROUNDS>
__device__ __forceinline__ void stageT(const char* g, long row0, long ldb,
                                       long k0b, char* l, int tid) {
#pragma unroll
  for (int r = 0; r < ROUNDS; ++r) {
    int o = r * 4096 + tid * 16;
    int row = o >> 6;
    int col = o & 63;
    gl_lds16(g + (row0 + row) * ldb + k0b + col, l + o);
  }
}

// 128x32 u16 tile (8 KB)
__device__ __forceinline__ void stage8k(const u16* gbase, long row0, int k0, int ld,
                                        char* lds, int tid) {
  stageT<2>((const char*)gbase, row0, (long)ld * 2, (long)k0 * 2, lds, tid);
}

// ---------------------------------------------------------------- converts
// blocks [0,8192): x -> xh bf16 + xd0/xd1 i8
//        [8192,10240): Wq,Wk -> digit i8 pairs
//        [10240,11264): Wv -> bf16 hi
__global__ void __launch_bounds__(256) convert_all(
    const float* __restrict__ x, const float* __restrict__ Wq,
    const float* __restrict__ Wk, const float* __restrict__ Wv,
    u16* __restrict__ xh, u8* __restrict__ xd0, u8* __restrict__ xd1,
    u8* __restrict__ wq0, u8* __restrict__ wq1,
    u8* __restrict__ wk0, u8* __restrict__ wk1,
    u16* __restrict__ wvh) {
  long b = blockIdx.x;
  if (b < 8192) {
    long i = b * 256 + threadIdx.x;
    f32x4 v = ((const f32x4*)x)[i];
    u16x4 h;
    u32 p0 = 0, p1 = 0;
#pragma unroll
    for (int j = 0; j < 4; ++j) {
      h[j] = f2bf(v[j]);
      int d0, d1;
      dig2(v[j], XC, XCI, XFI, d0, d1);
      p0 |= ((u32)(d0 & 255)) << (8 * j);
      p1 |= ((u32)(d1 & 255)) << (8 * j);
    }
    ((u16x4*)xh)[i] = h;
    ((u32*)xd0)[i] = p0;
    ((u32*)xd1)[i] = p1;
  } else if (b < 10240) {
    int w = (int)((b - 8192) >> 10);  // 0=q, 1=k
    const float* src = w ? Wk : Wq;
    u8* o0 = w ? wk0 : wq0;
    u8* o1 = w ? wk1 : wq1;
    long i = ((b - 8192) & 1023) * 256 + threadIdx.x;
    f32x4 v = ((const f32x4*)src)[i];
    u32 p0 = 0, p1 = 0;
#pragma unroll
    for (int j = 0; j < 4; ++j) {
      int d0, d1;
      dig2(v[j], WC, WCI, WFI, d0, d1);
      p0 |= ((u32)(d0 & 255)) << (8 * j);
      p1 |= ((u32)(d1 & 255)) << (8 * j);
    }
    ((u32*)o0)[i] = p0;
    ((u32*)o1)[i] = p1;
  } else {
    long i = (b - 10240) * 256 + threadIdx.x;
    f32x4 v = ((const f32x4*)Wv)[i];
    u16x4 h;
#pragma unroll
    for (int j = 0; j < 4; ++j) h[j] = f2bf(v[j]);
    ((u16x4*)wvh)[i] = h;
  }
}

// ---------------------------------------------------------------- q/k GEMM
// q[b,s,e] = x[b,s,:].W[e,:] + bias via 2-digit x 2-digit i8 (4 products).
// 128x128 block, 4 waves (2x2), wave-tile 64x64, K-64 steps, 32 KB LDS.
// z=0 -> q (Wq, bq), z=1 -> k (Wk, bk). Output: 2 i8 digits.
__global__ void __launch_bounds__(256) qk_gemm(
    const u8* __restrict__ xd0, const u8* __restrict__ xd1,
    const u8* __restrict__ wq0, const u8* __restrict__ wq1,
    const u8* __restrict__ wk0, const u8* __restrict__ wk1,
    const float* __restrict__ bq, const float* __restrict__ bk,
    u8* __restrict__ q0, u8* __restrict__ q1,
    u8* __restrict__ kd0, u8* __restrict__ kd1) {
  __shared__ char lds[32768];  // xd0 | xd1 | w0 | w1 (8 KB each)
  const int tid = threadIdx.x;
  const int z = blockIdx.z;
  const long m0 = (long)blockIdx.y * 128;
  const int n0 = blockIdx.x * 128;
  const int wave = tid >> 6, lane = tid & 63;
  const int wm = wave >> 1, wn = wave & 1;
  const int lr = lane & 15, lk = lane >> 4;

  const u8* w0 = z ? wk0 : wq0;
  const u8* w1 = z ? wk1 : wq1;
  const float* bias = z ? bk : bq;
  u8* o0 = z ? kd0 : q0;
  u8* o1 = z ? kd1 : q1;

  i32x4 accM[4][4] = {};  // d0*e0  scale 2^-13
  i32x4 accX[4][4] = {};  // d0*e1 + d1*e0  scale 2^-21
  i32x4 accY[4][4] = {};  // d1*e1  scale 2^-29

  for (int kk = 0; kk < Dd; kk += 64) {
    stageT<2>((const char*)xd0, m0, Dd, kk, lds + 0, tid);
    stageT<2>((const char*)xd1, m0, Dd, kk, lds + 8192, tid);
    stageT<2>((const char*)w0, n0, Dd, kk, lds + 16384, tid);
    stageT<2>((const char*)w1, n0, Dd, kk, lds + 24576, tid);
    __syncthreads();
    i32x4 b0[4], b1[4];
#pragma unroll
    for (int nt = 0; nt < 4; ++nt) {
      int rb = (wn * 64 + nt * 16 + lr) * 64 + lk * 16;
      b0[nt] = *(const i32x4*)(lds + 16384 + rb);
      b1[nt] = *(const i32x4*)(lds + 24576 + rb);
    }
#pragma unroll
    for (int mt = 0; mt < 4; ++mt) {
      int ra = (wm * 64 + mt * 16 + lr) * 64 + lk * 16;
      i32x4 a0 = *(const i32x4*)(lds + 0 + ra);
      i32x4 a1 = *(const i32x4*)(lds + 8192 + ra);
#pragma unroll
      for (int nt = 0; nt < 4; ++nt) {
        accM[mt][nt] = mfma_i8(a0, b0[nt], accM[mt][nt]);
        accX[mt][nt] = mfma_i8(a0, b1[nt], accX[mt][nt]);
        accX[mt][nt] = mfma_i8(a1, b0[nt], accX[mt][nt]);
        accY[mt][nt] = mfma_i8(a1, b1[nt], accY[mt][nt]);
      }
    }
    __syncthreads();
  }

#pragma unroll
  for (int mt = 0; mt < 4; ++mt)
#pragma unroll
    for (int nt = 0; nt < 4; ++nt)
#pragma unroll
      for (int r = 0; r < 4; ++r) {
        long gm = m0 + wm * 64 + mt * 16 + lk * 4 + r;
        int e = n0 + wn * 64 + nt * 16 + lr;
        float v = (float)accM[mt][nt][r] * SM_P +
                  (float)accX[mt][nt][r] * SX_P +
                  (float)accY[mt][nt][r] * SY_P + bias[e];
        int d0, d1;
        dig2(v, XC, XCI, XFI, d0, d1);
        long idx = gm * Dd + e;
        o0[idx] = (u8)d0;
        o1[idx] = (u8)d1;
      }
}

// ---------------------------------------------------------------- v GEMM
// v[b,s,e] = x.Wv + bv, single bf16 MFMA, f16 transposed output vt[b][e][s].
__global__ void __launch_bounds__(256) v_gemm(
    const u16* __restrict__ xh, const u16* __restrict__ wvh,
    const float* __restrict__ bv, u16* __restrict__ vt) {
  __shared__ char lds[16384];  // A | B
  const int tid = threadIdx.x;
  const long m0 = (long)blockIdx.y * 128;
  const int n0 = blockIdx.x * 128;
  const int wave = tid >> 6, lane = tid & 63;
  const int wm = wave >> 1, wn = wave & 1;
  const int lr = lane & 15, lk = lane >> 4;

  f32x4 acc[4][4] = {};

  for (int k0 = 0; k0 < Dd; k0 += 32) {
    stage8k(xh, m0, k0, Dd, lds + 0, tid);
    stage8k(wvh, n0, k0, Dd, lds + 8192, tid);
    __syncthreads();
    bf16x8 af[4], bf[4];
#pragma unroll
    for (int i = 0; i < 4; ++i) {
      int ra = (wm * 64 + i * 16 + lr) * 64 + lk * 16;
      int rb = (wn * 64 + i * 16 + lr) * 64 + lk * 16;
      af[i] = frag_ld(lds + ra);
      bf[i] = frag_ld(lds + 8192 + rb);
    }
#pragma unroll
    for (int mt = 0; mt < 4; ++mt)
#pragma unroll
      for (int nt = 0; nt < 4; ++nt)
        acc[mt][nt] = mfma_bf16(af[mt], bf[nt], acc[mt][nt]);
    __syncthreads();
  }

#pragma unroll
  for (int mt = 0; mt < 4; ++mt)
#pragma unroll
    for (int nt = 0; nt < 4; ++nt)
#pragma unroll
      for (int r = 0; r < 4; ++r) {
        long gm = m0 + wm * 64 + mt * 16 + lk * 4 + r;
        int e = n0 + wn * 64 + nt * 16 + lr;
        float v = acc[mt][nt][r] + bv[e];
        long b = gm >> 11, s = gm & 2047;
        vt[(b * Dd + e) * (long)Ss + s] = f2h(v);
      }
}

// ---------------------------------------------------------------- scores GEMM
// scores[b][i][j] = q[b,i,:].k[b,j,:] via pure 2-digit i8 MFMA (exact int acc)
__global__ void __launch_bounds__(256) score_gemm(
    const u8* __restrict__ q0, const u8* __restrict__ q1,
    const u8* __restrict__ kd0, const u8* __restrict__ kd1,
    float* __restrict__ scores) {
  __shared__ char lds[32768];  // q0 | q1 | k0 | k1 (8 KB each)
  const int tid = threadIdx.x;
  const int z = blockIdx.z;  // batch
  const long base = (long)z * Ss * Dd;
  const long m0 = (long)blockIdx.y * 128;
  const int n0 = blockIdx.x * 128;
  const int wave = tid >> 6, lane = tid & 63;
  const int wm = wave >> 1, wn = wave & 1;
  const int lr = lane & 15, lk = lane >> 4;

  i32x4 accM[4][4] = {};  // d0*d0   scale 2^-8
  i32x4 accX[4][4] = {};  // cross   scale 2^-16
  i32x4 accY[4][4] = {};  // d1*d1   scale 2^-24

  for (int kk = 0; kk < Dd; kk += 64) {
    stageT<2>((const char*)q0 + base, m0, Dd, kk, lds + 0, tid);
    stageT<2>((const char*)q1 + base, m0, Dd, kk, lds + 8192, tid);
    stageT<2>((const char*)kd0 + base, n0, Dd, kk, lds + 16384, tid);
    stageT<2>((const char*)kd1 + base, n0, Dd, kk, lds + 24576, tid);
    __syncthreads();
    i32x4 b0[4], b1[4];
#pragma unroll
    for (int nt = 0; nt < 4; ++nt) {
      int rb = (wn * 64 + nt * 16 + lr) * 64 + lk * 16;
      b0[nt] = *(const i32x4*)(lds + 16384 + rb);
      b1[nt] = *(const i32x4*)(lds + 24576 + rb);
    }
#pragma unroll
    for (int mt = 0; mt < 4; ++mt) {
      int ra = (wm * 64 + mt * 16 + lr) * 64 + lk * 16;
      i32x4 a0 = *(const i32x4*)(lds + 0 + ra);
      i32x4 a1 = *(const i32x4*)(lds + 8192 + ra);
#pragma unroll
      for (int nt = 0; nt < 4; ++nt) {
        accM[mt][nt] = mfma_i8(a0, b0[nt], accM[mt][nt]);
        accX[mt][nt] = mfma_i8(a0, b1[nt], accX[mt][nt]);
        accX[mt][nt] = mfma_i8(a1, b0[nt], accX[mt][nt]);
        accY[mt][nt] = mfma_i8(a1, b1[nt], accY[mt][nt]);
      }
    }
    __syncthreads();
  }

  float* srow = scores + (long)z * Ss * Ss;
#pragma unroll
  for (int mt = 0; mt < 4; ++mt)
#pragma unroll
    for (int nt = 0; nt < 4; ++nt)
#pragma unroll
      for (int r = 0; r < 4; ++r) {
        long i = m0 + wm * 64 + mt * 16 + lk * 4 + r;
        int j = n0 + wn * 64 + nt * 16 + lr;
        srow[i * Ss + j] = (float)accM[mt][nt][r] * S00 +
                           (float)accX[mt][nt][r] * S01 +
                           (float)accY[mt][nt][r] * S11;
      }
}

// ---------------------------------------------------------------- softmax
// one block per row; reads 2048 fp32 scores, writes 2048 f16 P (dense).
__global__ void __launch_bounds__(256) softmax_rows(const float* __restrict__ scores,
                                                    u16* __restrict__ P) {
  const long r = blockIdx.x;
  const float* row = scores + r * Ss;
  u16* prow = P + r * Ss;
  const int t = threadIdx.x;
  const int wave = t >> 6, lane = t & 63;
  f32x4 v0 = ((const f32x4*)row)[t * 2];
  f32x4 v1 = ((const f32x4*)row)[t * 2 + 1];
  float a[8];
#pragma unroll
  for (int j = 0; j < 4; ++j) { a[j] = v0[j]; a[4 + j] = v1[j]; }

  float m = a[0];
#pragma unroll
  for (int j = 1; j < 8; ++j) m = fmaxf(m, a[j]);
#pragma unroll
  for (int off = 32; off >= 1; off >>= 1) m = fmaxf(m, __shfl_xor(m, off));
  __shared__ float red[4];
  if (lane == 0) red[wave] = m;
  __syncthreads();
  m = fmaxf(fmaxf(red[0], red[1]), fmaxf(red[2], red[3]));

  float e[8];
  float s = 0.f;
#pragma unroll
  for (int j = 0; j < 8; ++j) { e[j] = __expf(a[j] - m); s += e[j]; }
#pragma unroll
  for (int off = 32; off >= 1; off >>= 1) s += __shfl_xor(s, off);
  __syncthreads();
  if (lane == 0) red[wave] = s;
  __syncthreads();
  s = red[0] + red[1] + red[2] + red[3];
  float inv = 1.0f / s;

  u16x8 pk;
#pragma unroll
  for (int j = 0; j < 8; ++j) pk[j] = f2h(e[j] * inv);
  ((u16x8*)prow)[t] = pk;
}

// ---------------------------------------------------------------- PV GEMM
// out[b][i][e] = sum_j P[b][i][j] * vt[b][e][j]   (f16, dense P)
__global__ void __launch_bounds__(256) pv_gemm(const u16* __restrict__ P,
                                               const u16* __restrict__ vt,
                                               float* __restrict__ out) {
  __shared__ char lds[16384];  // A | B
  const int tid = threadIdx.x;
  const int z = blockIdx.z;  // batch
  const u16* A = P + (long)z * Ss * Ss;    // dense [2048][2048] f16
  const u16* Bp = vt + (long)z * Dd * Ss;  // [1024][2048]
  const long m0 = (long)blockIdx.y * 128;
  const int n0 = blockIdx.x * 128;

  const int wave = tid >> 6, lane = tid & 63;
  const int wm = wave >> 1, wn = wave & 1;
  const int lr = lane & 15, lk = lane >> 4;

  f32x4 acc[4][4] = {};

  for (int k0 = 0; k0 < Ss; k0 += 32) {
    stage8k(A, m0, k0, Ss, lds + 0, tid);
    stage8k(Bp, n0, k0, Ss, lds + 8192, tid);
    __syncthreads();
    f16x8 af[4], bf[4];
#pragma unroll
    for (int i = 0; i < 4; ++i) {
      int ra = (wm * 64 + i * 16 + lr) * 64 + lk * 16;
      int rb = (wn * 64 + i * 16 + lr) * 64 + lk * 16;
      af[i] = frag_ld_h(lds + ra);
      bf[i] = frag_ld_h(lds + 8192 + rb);
    }
#pragma unroll
    for (int mt = 0; mt < 4; ++mt)
#pragma unroll
      for (int nt = 0; nt < 4; ++nt)
        acc[mt][nt] = __builtin_amdgcn_mfma_f32_16x16x32_f16(af[mt], bf[nt], acc[mt][nt], 0, 0, 0);
    __syncthreads();
  }

  float* orow = out + (long)z * Ss * Dd;
#pragma unroll
  for (int mt = 0; mt < 4; ++mt)
#pragma unroll
    for (int nt = 0; nt < 4; ++nt)
#pragma unroll
      for (int r = 0; r < 4; ++r) {
        long i = m0 + wm * 64 + mt * 16 + lk * 4 + r;
        int e = n0 + wn * 64 + nt * 16 + lr;
        orow[i * Dd + e] = acc[mt][nt][r];
      }
}

// ---------------------------------------------------------------- launch
extern "C" void kernel_launch(void* const* d_in, const int* in_sizes, int n_in,
                              void* d_out, int out_size, void* d_ws, size_t ws_size,
                              hipStream_t stream) {
  const float* x = (const float*)d_in[0];
  const float* Wq = (const float*)d_in[1];
  const float* bq = (const float*)d_in[2];
  const float* Wk = (const float*)d_in[3];
  const float* bk = (const float*)d_in[4];
  const float* Wv = (const float*)d_in[5];
  const float* bv = (const float*)d_in[6];
  float* out = (float*)d_out;

  // workspace carve (~150 MiB)
  char* p = (char*)d_ws;
  float* scores = (float*)p;           // 64 MB; x buffers aliased underneath
  u16* xh = (u16*)p;                   //   (dead before scores written)
  u8* xd0 = (u8*)(p + 16777216);
  u8* xd1 = (u8*)(p + 25165824);
  p += 67108864;
  u8* q0 = (u8*)p; p += 8388608;
  u8* q1 = (u8*)p; p += 8388608;
  u8* kd0 = (u8*)p; p += 8388608;
  u8* kd1 = (u8*)p; p += 8388608;
  u16* Pbuf = (u16*)p; p += 33554432;  // dense f16 P [4][2048][2048]
  u16* vt = (u16*)p; p += 16777216;
  u8* wq0 = (u8*)p; p += 1048576;
  u8* wq1 = (u8*)p; p += 1048576;
  u8* wk0 = (u8*)p; p += 1048576;
  u8* wk1 = (u8*)p; p += 1048576;
  u16* wvh = (u16*)p; p += 2097152;

  // 1. converts
  convert_all<<<dim3(11264), dim3(256), 0, stream>>>(
      x, Wq, Wk, Wv, xh, xd0, xd1, wq0, wq1, wk0, wk1, wvh);

  // 2a. q/k projections (i8 digit GEMM)
  qk_gemm<<<dim3(Dd / 128, Mtot / 128, 2), dim3(256), 0, stream>>>(
      xd0, xd1, wq0, wq1, wk0, wk1, bq, bk, q0, q1, kd0, kd1);

  // 2b. v projection (bf16, transposed f16 out)
  v_gemm<<<dim3(Dd / 128, Mtot / 128), dim3(256), 0, stream>>>(xh, wvh, bv, vt);

  // 3. scores = q k^T (pure i8)
  score_gemm<<<dim3(Ss / 128, Ss / 128, Bb), dim3(256), 0, stream>>>(
      q0, q1, kd0, kd1, scores);

  // 4. softmax rows -> dense P
  softmax_rows<<<dim3(Bb * Ss), dim3(256), 0, stream>>>(scores, Pbuf);

  // 5. out = P @ v
  pv_gemm<<<dim3(Dd / 128, Ss / 128, Bb), dim3(256), 0, stream>>>(Pbuf, vt, out);
}

// Round 7
// 418.101 us; speedup vs baseline: 1.0337x; 1.0337x over previous
//
#include <hip/hip_runtime.h>

// SelfAttention: B=4, S=2048, D=1024, fp32 in/out.
// q=x@Wq^T+bq, k=..., v=...; out = softmax(q k^T) @ v   (no 1/sqrt(d) scale)
//
// Precision plan (all GEMM cores in MFMA):
//  - q/k projections: 2-digit i8 x 2-digit i8, ALL 4 digit products kept
//    (exact integer accumulation). x = d0*2^-4 + d1*2^-12,
//    W = e0*2^-9 + e1*2^-17. delta-q ~ 1.2e-4 std.
//  - q/k requantized to 2 i8 digits (2^-4 / 2^-12) in the epilogue.
//  - scores: 2-digit i8 (M=d0d0 2^-8, X=cross 2^-16, Y=d1d1 2^-24). Exact.
//  - v projection: single bf16 MFMA (dv ~1.4e-3, harmless); PV GEMM in f16.
// P has its own dense buffer (R4 post-mortem: in-place P alias breaks replay).
// R7: i8 kernels are occupancy-bound (VGPR 212 -> 2 blocks/CU). K-loop
// unrolled to 128/stage (64 KB LDS, still 2 blocks/CU) to halve barrier count.

#define Bb 4
#define Ss 2048
#define Dd 1024
#define Mtot 8192  // B*S

typedef __bf16 bf16x8 __attribute__((ext_vector_type(8)));
typedef _Float16 f16x8 __attribute__((ext_vector_type(8)));
typedef float f32x4 __attribute__((ext_vector_type(4)));
typedef int i32x4 __attribute__((ext_vector_type(4)));
typedef unsigned short u16;
typedef unsigned int u32;
typedef unsigned char u8;
typedef u16 u16x8 __attribute__((ext_vector_type(8)));
typedef u16 u16x4 __attribute__((ext_vector_type(4)));
typedef void __attribute__((address_space(1))) gvoid_t;
typedef void __attribute__((address_space(3))) svoid_t;

// ---- digit scales (all powers of two; products align exactly) ----
#define XC 0.0625f
#define XCI 16.f
#define XFI 4096.f
#define WC 1.953125e-3f
#define WCI 512.f
#define WFI 131072.f
// projection accumulator scales
#define SM_P 1.220703125e-4f          // 2^-13
#define SX_P 4.76837158203125e-7f     // 2^-21
#define SY_P 1.862645149230957e-9f    // 2^-29
// score accumulator scales
#define S00 3.90625e-3f               // 2^-8
#define S01 1.52587890625e-5f         // 2^-16
#define S11 5.9604644775390625e-8f    // 2^-24

__device__ __forceinline__ void gl_lds16(const void* g, void* l) {
  __builtin_amdgcn_global_load_lds((gvoid_t*)g, (svoid_t*)l, 16, 0, 0);
}

__device__ __forceinline__ u16 f2bf(float f) {  // RNE float->bf16
  u32 u = __builtin_bit_cast(u32, f);
  u = (u + 0x7FFFu + ((u >> 16) & 1u)) >> 16;
  return (u16)u;
}
__device__ __forceinline__ u16 f2h(float f) {
  return __builtin_bit_cast(u16, (_Float16)f);
}
__device__ __forceinline__ bf16x8 frag_ld(const char* p) {
  u16x8 v = *(const u16x8*)p;
  return __builtin_bit_cast(bf16x8, v);
}
__device__ __forceinline__ f16x8 frag_ld_h(const char* p) {
  u16x8 v = *(const u16x8*)p;
  return __builtin_bit_cast(f16x8, v);
}
__device__ __forceinline__ f32x4 mfma_bf16(bf16x8 a, bf16x8 b, f32x4 c) {
  return __builtin_amdgcn_mfma_f32_16x16x32_bf16(a, b, c, 0, 0, 0);
}
__device__ __forceinline__ i32x4 mfma_i8(i32x4 a, i32x4 b, i32x4 c) {
  return __builtin_amdgcn_mfma_i32_16x16x64_i8(a, b, c, 0, 0, 0);
}
// split v into two clamped i8 digits: v ~= d0*cs + d1*(1/fi)
__device__ __forceinline__ void dig2(float v, float cs, float ci, float fi,
                                     int& d0, int& d1) {
  float t = fminf(fmaxf(v * ci, -127.f), 127.f);
  d0 = __float2int_rn(t);
  float res = v - (float)d0 * cs;
  float u = fminf(fmaxf(res * fi, -127.f), 127.f);
  d1 = __float2int_rn(u);
}

// stage a tile with 64-byte rows to LDS; ROUNDS*4 KB, linear row-major.
template <int ROUNDS>
__device__ __forceinline__ void stageT(const char* g, long row0, long ldb,
                                       long k0b, char* l, int tid) {
#pragma unroll
  for (int r = 0; r < ROUNDS; ++r) {
    int o = r * 4096 + tid * 16;
    int row = o >> 6;
    int col = o & 63;
    gl_lds16(g + (row0 + row) * ldb + k0b + col, l + o);
  }
}

// 128x32 u16 tile (8 KB)
__device__ __forceinline__ void stage8k(const u16* gbase, long row0, int k0, int ld,
                                        char* lds, int tid) {
  stageT<2>((const char*)gbase, row0, (long)ld * 2, (long)k0 * 2, lds, tid);
}

// ---------------------------------------------------------------- converts
__global__ void __launch_bounds__(256) convert_all(
    const float* __restrict__ x, const float* __restrict__ Wq,
    const float* __restrict__ Wk, const float* __restrict__ Wv,
    u16* __restrict__ xh, u8* __restrict__ xd0, u8* __restrict__ xd1,
    u8* __restrict__ wq0, u8* __restrict__ wq1,
    u8* __restrict__ wk0, u8* __restrict__ wk1,
    u16* __restrict__ wvh) {
  long b = blockIdx.x;
  if (b < 8192) {
    long i = b * 256 + threadIdx.x;
    f32x4 v = ((const f32x4*)x)[i];
    u16x4 h;
    u32 p0 = 0, p1 = 0;
#pragma unroll
    for (int j = 0; j < 4; ++j) {
      h[j] = f2bf(v[j]);
      int d0, d1;
      dig2(v[j], XC, XCI, XFI, d0, d1);
      p0 |= ((u32)(d0 & 255)) << (8 * j);
      p1 |= ((u32)(d1 & 255)) << (8 * j);
    }
    ((u16x4*)xh)[i] = h;
    ((u32*)xd0)[i] = p0;
    ((u32*)xd1)[i] = p1;
  } else if (b < 10240) {
    int w = (int)((b - 8192) >> 10);  // 0=q, 1=k
    const float* src = w ? Wk : Wq;
    u8* o0 = w ? wk0 : wq0;
    u8* o1 = w ? wk1 : wq1;
    long i = ((b - 8192) & 1023) * 256 + threadIdx.x;
    f32x4 v = ((const f32x4*)src)[i];
    u32 p0 = 0, p1 = 0;
#pragma unroll
    for (int j = 0; j < 4; ++j) {
      int d0, d1;
      dig2(v[j], WC, WCI, WFI, d0, d1);
      p0 |= ((u32)(d0 & 255)) << (8 * j);
      p1 |= ((u32)(d1 & 255)) << (8 * j);
    }
    ((u32*)o0)[i] = p0;
    ((u32*)o1)[i] = p1;
  } else {
    long i = (b - 10240) * 256 + threadIdx.x;
    f32x4 v = ((const f32x4*)Wv)[i];
    u16x4 h;
#pragma unroll
    for (int j = 0; j < 4; ++j) h[j] = f2bf(v[j]);
    ((u16x4*)wvh)[i] = h;
  }
}

// ---------------------------------------------------------------- q/k GEMM
// 128x128 block, 4 waves (2x2), wave-tile 64x64, K-128 stages, 64 KB LDS.
// LDS: 8 x 8KB chunks: A0lo A0hi A1lo A1hi | B0lo B0hi B1lo B1hi
__global__ void __launch_bounds__(256) qk_gemm(
    const u8* __restrict__ xd0, const u8* __restrict__ xd1,
    const u8* __restrict__ wq0, const u8* __restrict__ wq1,
    const u8* __restrict__ wk0, const u8* __restrict__ wk1,
    const float* __restrict__ bq, const float* __restrict__ bk,
    u8* __restrict__ q0, u8* __restrict__ q1,
    u8* __restrict__ kd0, u8* __restrict__ kd1) {
  __shared__ char lds[65536];
  const int tid = threadIdx.x;
  const int z = blockIdx.z;
  const long m0 = (long)blockIdx.y * 128;
  const int n0 = blockIdx.x * 128;
  const int wave = tid >> 6, lane = tid & 63;
  const int wm = wave >> 1, wn = wave & 1;
  const int lr = lane & 15, lk = lane >> 4;

  const u8* w0 = z ? wk0 : wq0;
  const u8* w1 = z ? wk1 : wq1;
  const float* bias = z ? bk : bq;
  u8* o0 = z ? kd0 : q0;
  u8* o1 = z ? kd1 : q1;

  i32x4 accM[4][4] = {};  // d0*e0  scale 2^-13
  i32x4 accX[4][4] = {};  // cross  scale 2^-21
  i32x4 accY[4][4] = {};  // d1*e1  scale 2^-29

  for (int kk = 0; kk < Dd; kk += 128) {
    stageT<2>((const char*)xd0, m0, Dd, kk, lds + 0, tid);
    stageT<2>((const char*)xd0, m0, Dd, kk + 64, lds + 8192, tid);
    stageT<2>((const char*)xd1, m0, Dd, kk, lds + 16384, tid);
    stageT<2>((const char*)xd1, m0, Dd, kk + 64, lds + 24576, tid);
    stageT<2>((const char*)w0, n0, Dd, kk, lds + 32768, tid);
    stageT<2>((const char*)w0, n0, Dd, kk + 64, lds + 40960, tid);
    stageT<2>((const char*)w1, n0, Dd, kk, lds + 49152, tid);
    stageT<2>((const char*)w1, n0, Dd, kk + 64, lds + 57344, tid);
    __syncthreads();
#pragma unroll
    for (int h = 0; h < 2; ++h) {
      const int hb = h * 8192;
      i32x4 b0[4], b1[4];
#pragma unroll
      for (int nt = 0; nt < 4; ++nt) {
        int rb = (wn * 64 + nt * 16 + lr) * 64 + lk * 16;
        b0[nt] = *(const i32x4*)(lds + 32768 + hb + rb);
        b1[nt] = *(const i32x4*)(lds + 49152 + hb + rb);
      }
#pragma unroll
      for (int mt = 0; mt < 4; ++mt) {
        int ra = (wm * 64 + mt * 16 + lr) * 64 + lk * 16;
        i32x4 a0 = *(const i32x4*)(lds + 0 + hb + ra);
        i32x4 a1 = *(const i32x4*)(lds + 16384 + hb + ra);
#pragma unroll
        for (int nt = 0; nt < 4; ++nt) {
          accM[mt][nt] = mfma_i8(a0, b0[nt], accM[mt][nt]);
          accX[mt][nt] = mfma_i8(a0, b1[nt], accX[mt][nt]);
          accX[mt][nt] = mfma_i8(a1, b0[nt], accX[mt][nt]);
          accY[mt][nt] = mfma_i8(a1, b1[nt], accY[mt][nt]);
        }
      }
    }
    __syncthreads();
  }

#pragma unroll
  for (int mt = 0; mt < 4; ++mt)
#pragma unroll
    for (int nt = 0; nt < 4; ++nt)
#pragma unroll
      for (int r = 0; r < 4; ++r) {
        long gm = m0 + wm * 64 + mt * 16 + lk * 4 + r;
        int e = n0 + wn * 64 + nt * 16 + lr;
        float v = (float)accM[mt][nt][r] * SM_P +
                  (float)accX[mt][nt][r] * SX_P +
                  (float)accY[mt][nt][r] * SY_P + bias[e];
        int d0, d1;
        dig2(v, XC, XCI, XFI, d0, d1);
        long idx = gm * Dd + e;
        o0[idx] = (u8)d0;
        o1[idx] = (u8)d1;
      }
}

// ---------------------------------------------------------------- v GEMM
__global__ void __launch_bounds__(256) v_gemm(
    const u16* __restrict__ xh, const u16* __restrict__ wvh,
    const float* __restrict__ bv, u16* __restrict__ vt) {
  __shared__ char lds[16384];  // A | B
  const int tid = threadIdx.x;
  const long m0 = (long)blockIdx.y * 128;
  const int n0 = blockIdx.x * 128;
  const int wave = tid >> 6, lane = tid & 63;
  const int wm = wave >> 1, wn = wave & 1;
  const int lr = lane & 15, lk = lane >> 4;

  f32x4 acc[4][4] = {};

  for (int k0 = 0; k0 < Dd; k0 += 32) {
    stage8k(xh, m0, k0, Dd, lds + 0, tid);
    stage8k(wvh, n0, k0, Dd, lds + 8192, tid);
    __syncthreads();
    bf16x8 af[4], bf[4];
#pragma unroll
    for (int i = 0; i < 4; ++i) {
      int ra = (wm * 64 + i * 16 + lr) * 64 + lk * 16;
      int rb = (wn * 64 + i * 16 + lr) * 64 + lk * 16;
      af[i] = frag_ld(lds + ra);
      bf[i] = frag_ld(lds + 8192 + rb);
    }
#pragma unroll
    for (int mt = 0; mt < 4; ++mt)
#pragma unroll
      for (int nt = 0; nt < 4; ++nt)
        acc[mt][nt] = mfma_bf16(af[mt], bf[nt], acc[mt][nt]);
    __syncthreads();
  }

#pragma unroll
  for (int mt = 0; mt < 4; ++mt)
#pragma unroll
    for (int nt = 0; nt < 4; ++nt)
#pragma unroll
      for (int r = 0; r < 4; ++r) {
        long gm = m0 + wm * 64 + mt * 16 + lk * 4 + r;
        int e = n0 + wn * 64 + nt * 16 + lr;
        float v = acc[mt][nt][r] + bv[e];
        long b = gm >> 11, s = gm & 2047;
        vt[(b * Dd + e) * (long)Ss + s] = f2h(v);
      }
}

// ---------------------------------------------------------------- scores GEMM
// same K-128 staged structure as qk_gemm.
__global__ void __launch_bounds__(256) score_gemm(
    const u8* __restrict__ q0, const u8* __restrict__ q1,
    const u8* __restrict__ kd0, const u8* __restrict__ kd1,
    float* __restrict__ scores) {
  __shared__ char lds[65536];
  const int tid = threadIdx.x;
  const int z = blockIdx.z;  // batch
  const long base = (long)z * Ss * Dd;
  const long m0 = (long)blockIdx.y * 128;
  const int n0 = blockIdx.x * 128;
  const int wave = tid >> 6, lane = tid & 63;
  const int wm = wave >> 1, wn = wave & 1;
  const int lr = lane & 15, lk = lane >> 4;

  i32x4 accM[4][4] = {};  // d0*d0   scale 2^-8
  i32x4 accX[4][4] = {};  // cross   scale 2^-16
  i32x4 accY[4][4] = {};  // d1*d1   scale 2^-24

  for (int kk = 0; kk < Dd; kk += 128) {
    stageT<2>((const char*)q0 + base, m0, Dd, kk, lds + 0, tid);
    stageT<2>((const char*)q0 + base, m0, Dd, kk + 64, lds + 8192, tid);
    stageT<2>((const char*)q1 + base, m0, Dd, kk, lds + 16384, tid);
    stageT<2>((const char*)q1 + base, m0, Dd, kk + 64, lds + 24576, tid);
    stageT<2>((const char*)kd0 + base, n0, Dd, kk, lds + 32768, tid);
    stageT<2>((const char*)kd0 + base, n0, Dd, kk + 64, lds + 40960, tid);
    stageT<2>((const char*)kd1 + base, n0, Dd, kk, lds + 49152, tid);
    stageT<2>((const char*)kd1 + base, n0, Dd, kk + 64, lds + 57344, tid);
    __syncthreads();
#pragma unroll
    for (int h = 0; h < 2; ++h) {
      const int hb = h * 8192;
      i32x4 b0[4], b1[4];
#pragma unroll
      for (int nt = 0; nt < 4; ++nt) {
        int rb = (wn * 64 + nt * 16 + lr) * 64 + lk * 16;
        b0[nt] = *(const i32x4*)(lds + 32768 + hb + rb);
        b1[nt] = *(const i32x4*)(lds + 49152 + hb + rb);
      }
#pragma unroll
      for (int mt = 0; mt < 4; ++mt) {
        int ra = (wm * 64 + mt * 16 + lr) * 64 + lk * 16;
        i32x4 a0 = *(const i32x4*)(lds + 0 + hb + ra);
        i32x4 a1 = *(const i32x4*)(lds + 16384 + hb + ra);
#pragma unroll
        for (int nt = 0; nt < 4; ++nt) {
          accM[mt][nt] = mfma_i8(a0, b0[nt], accM[mt][nt]);
          accX[mt][nt] = mfma_i8(a0, b1[nt], accX[mt][nt]);
          accX[mt][nt] = mfma_i8(a1, b0[nt], accX[mt][nt]);
          accY[mt][nt] = mfma_i8(a1, b1[nt], accY[mt][nt]);
        }
      }
    }
    __syncthreads();
  }

  float* srow = scores + (long)z * Ss * Ss;
#pragma unroll
  for (int mt = 0; mt < 4; ++mt)
#pragma unroll
    for (int nt = 0; nt < 4; ++nt)
#pragma unroll
      for (int r = 0; r < 4; ++r) {
        long i = m0 + wm * 64 + mt * 16 + lk * 4 + r;
        int j = n0 + wn * 64 + nt * 16 + lr;
        srow[i * Ss + j] = (float)accM[mt][nt][r] * S00 +
                           (float)accX[mt][nt][r] * S01 +
                           (float)accY[mt][nt][r] * S11;
      }
}

// ---------------------------------------------------------------- softmax
__global__ void __launch_bounds__(256) softmax_rows(const float* __restrict__ scores,
                                                    u16* __restrict__ P) {
  const long r = blockIdx.x;
  const float* row = scores + r * Ss;
  u16* prow = P + r * Ss;
  const int t = threadIdx.x;
  const int wave = t >> 6, lane = t & 63;
  f32x4 v0 = ((const f32x4*)row)[t * 2];
  f32x4 v1 = ((const f32x4*)row)[t * 2 + 1];
  float a[8];
#pragma unroll
  for (int j = 0; j < 4; ++j) { a[j] = v0[j]; a[4 + j] = v1[j]; }

  float m = a[0];
#pragma unroll
  for (int j = 1; j < 8; ++j) m = fmaxf(m, a[j]);
#pragma unroll
  for (int off = 32; off >= 1; off >>= 1) m = fmaxf(m, __shfl_xor(m, off));
  __shared__ float red[4];
  if (lane == 0) red[wave] = m;
  __syncthreads();
  m = fmaxf(fmaxf(red[0], red[1]), fmaxf(red[2], red[3]));

  float e[8];
  float s = 0.f;
#pragma unroll
  for (int j = 0; j < 8; ++j) { e[j] = __expf(a[j] - m); s += e[j]; }
#pragma unroll
  for (int off = 32; off >= 1; off >>= 1) s += __shfl_xor(s, off);
  __syncthreads();
  if (lane == 0) red[wave] = s;
  __syncthreads();
  s = red[0] + red[1] + red[2] + red[3];
  float inv = 1.0f / s;

  u16x8 pk;
#pragma unroll
  for (int j = 0; j < 8; ++j) pk[j] = f2h(e[j] * inv);
  ((u16x8*)prow)[t] = pk;
}

// ---------------------------------------------------------------- PV GEMM
__global__ void __launch_bounds__(256) pv_gemm(const u16* __restrict__ P,
                                               const u16* __restrict__ vt,
                                               float* __restrict__ out) {
  __shared__ char lds[16384];  // A | B
  const int tid = threadIdx.x;
  const int z = blockIdx.z;  // batch
  const u16* A = P + (long)z * Ss * Ss;    // dense [2048][2048] f16
  const u16* Bp = vt + (long)z * Dd * Ss;  // [1024][2048]
  const long m0 = (long)blockIdx.y * 128;
  const int n0 = blockIdx.x * 128;

  const int wave = tid >> 6, lane = tid & 63;
  const int wm = wave >> 1, wn = wave & 1;
  const int lr = lane & 15, lk = lane >> 4;

  f32x4 acc[4][4] = {};

  for (int k0 = 0; k0 < Ss; k0 += 32) {
    stage8k(A, m0, k0, Ss, lds + 0, tid);
    stage8k(Bp, n0, k0, Ss, lds + 8192, tid);
    __syncthreads();
    f16x8 af[4], bf[4];
#pragma unroll
    for (int i = 0; i < 4; ++i) {
      int ra = (wm * 64 + i * 16 + lr) * 64 + lk * 16;
      int rb = (wn * 64 + i * 16 + lr) * 64 + lk * 16;
      af[i] = frag_ld_h(lds + ra);
      bf[i] = frag_ld_h(lds + 8192 + rb);
    }
#pragma unroll
    for (int mt = 0; mt < 4; ++mt)
#pragma unroll
      for (int nt = 0; nt < 4; ++nt)
        acc[mt][nt] = __builtin_amdgcn_mfma_f32_16x16x32_f16(af[mt], bf[nt], acc[mt][nt], 0, 0, 0);
    __syncthreads();
  }

  float* orow = out + (long)z * Ss * Dd;
#pragma unroll
  for (int mt = 0; mt < 4; ++mt)
#pragma unroll
    for (int nt = 0; nt < 4; ++nt)
#pragma unroll
      for (int r = 0; r < 4; ++r) {
        long i = m0 + wm * 64 + mt * 16 + lk * 4 + r;
        int e = n0 + wn * 64 + nt * 16 + lr;
        orow[i * Dd + e] = acc[mt][nt][r];
      }
}

// ---------------------------------------------------------------- launch
extern "C" void kernel_launch(void* const* d_in, const int* in_sizes, int n_in,
                              void* d_out, int out_size, void* d_ws, size_t ws_size,
                              hipStream_t stream) {
  const float* x = (const float*)d_in[0];
  const float* Wq = (const float*)d_in[1];
  const float* bq = (const float*)d_in[2];
  const float* Wk = (const float*)d_in[3];
  const float* bk = (const float*)d_in[4];
  const float* Wv = (const float*)d_in[5];
  const float* bv = (const float*)d_in[6];
  float* out = (float*)d_out;

  // workspace carve (~150 MiB)
  char* p = (char*)d_ws;
  float* scores = (float*)p;           // 64 MB; x buffers aliased underneath
  u16* xh = (u16*)p;                   //   (dead before scores written)
  u8* xd0 = (u8*)(p + 16777216);
  u8* xd1 = (u8*)(p + 25165824);
  p += 67108864;
  u8* q0 = (u8*)p; p += 8388608;
  u8* q1 = (u8*)p; p += 8388608;
  u8* kd0 = (u8*)p; p += 8388608;
  u8* kd1 = (u8*)p; p += 8388608;
  u16* Pbuf = (u16*)p; p += 33554432;  // dense f16 P [4][2048][2048]
  u16* vt = (u16*)p; p += 16777216;
  u8* wq0 = (u8*)p; p += 1048576;
  u8* wq1 = (u8*)p; p += 1048576;
  u8* wk0 = (u8*)p; p += 1048576;
  u8* wk1 = (u8*)p; p += 1048576;
  u16* wvh = (u16*)p; p += 2097152;

  // 1. converts
  convert_all<<<dim3(11264), dim3(256), 0, stream>>>(
      x, Wq, Wk, Wv, xh, xd0, xd1, wq0, wq1, wk0, wk1, wvh);

  // 2a. q/k projections (i8 digit GEMM, K-128 stages)
  qk_gemm<<<dim3(Dd / 128, Mtot / 128, 2), dim3(256), 0, stream>>>(
      xd0, xd1, wq0, wq1, wk0, wk1, bq, bk, q0, q1, kd0, kd1);

  // 2b. v projection (bf16, transposed f16 out)
  v_gemm<<<dim3(Dd / 128, Mtot / 128), dim3(256), 0, stream>>>(xh, wvh, bv, vt);

  // 3. scores = q k^T (pure i8, K-128 stages)
  score_gemm<<<dim3(Ss / 128, Ss / 128, Bb), dim3(256), 0, stream>>>(
      q0, q1, kd0, kd1, scores);

  // 4. softmax rows -> dense P
  softmax_rows<<<dim3(Bb * Ss), dim3(256), 0, stream>>>(scores, Pbuf);

  // 5. out = P @ v
  pv_gemm<<<dim3(Dd / 128, Ss / 128, Bb), dim3(256), 0, stream>>>(Pbuf, vt, out);
}